// Round 8
// baseline (16.472 us; speedup 1.0000x reference)
//
#include <hip/hip_runtime.h>
#include <hip/hip_bf16.h>
#include <math.h>

#define LOG2PI 1.8378770664093453f

typedef __attribute__((ext_vector_type(8))) short bf16x8;
typedef __attribute__((ext_vector_type(4))) float f32x4;

__device__ __forceinline__ ushort f2bf(float f) {
    __hip_bfloat16 h = __float2bfloat16(f);
    return *reinterpret_cast<ushort*>(&h);
}

// ws layout (floats): part[128*32] | base[128]

// grid = 512 blocks: tb = bid & 31 (t-chunk of 64), sc = bid >> 5 (8 states
// = 64 sm columns). 1024 threads = 16 waves, 2 blocks/CU -> 8 waves/SIMD.
// wave w (wr = w&3, wc = w>>2) owns C-tile rows [wr*16,+16) x cols
// [wc*16,+16) via 1 tile of mfma_f32_16x16x32_bf16, K=128
// (k = [x^2 | x] . [iv | -2 mu iv]).
__global__ __launch_bounds__(1024) void emis_mfma_kernel(
    const float* __restrict__ X,
    const float* __restrict__ means,
    const float* __restrict__ log_vars,
    const float* __restrict__ weight_logits,
    const float* __restrict__ trans_logits,
    float* __restrict__ part,              // [128*32]
    float* __restrict__ base) {            // [128]
    // A: [64 t][128 k] bf16, row stride 256B, XOR-swizzled
    // B: [64 n][128 k] bf16 (n = sm-local), row stride 256B, XOR-swizzled
    __shared__ __align__(16) char A_l[64 * 256];
    __shared__ __align__(16) char B_l[64 * 256];
    __shared__ float soff_l[64];
    __shared__ float wred[16][2];

    const int tb = blockIdx.x & 31;
    const int sc = blockIdx.x >> 5;
    const int tid = threadIdx.x;
    const int w  = tid >> 6;               // 0..15
    const int ln = tid & 63;
    const int wr = w & 3;                  // row tile (16 t-rows)
    const int wc = w >> 2;                 // col tile (16 cols)
    const int t0 = tb * 64;

    // ---- stage A: x^2 (k=0..63), x (k=64..127), bf16, swizzled ------------
    {
        const float4* Xv = (const float4*)(X + (size_t)t0 * 64);
        int r  = tid >> 4;                 // t row 0..63
        int d4 = tid & 15;                 // float4 col -> d = d4*4
        float4 x = Xv[tid];
        int swz = (r & 7) << 4;
        ushort4 sq = { f2bf(x.x * x.x), f2bf(x.y * x.y),
                       f2bf(x.z * x.z), f2bf(x.w * x.w) };
        ushort4 xl = { f2bf(x.x), f2bf(x.y), f2bf(x.z), f2bf(x.w) };
        *(ushort4*)(A_l + r * 256 + ((d4 * 8) ^ swz)) = sq;
        *(ushort4*)(A_l + r * 256 + ((128 + d4 * 8) ^ swz)) = xl;
    }

    // ---- stage B + soff: wave w handles n = w*4 .. w*4+3, lane = d ---------
    // soff[n] = -0.5*( sum_d(lv + mu^2*iv) + 64*log2pi )
    #pragma unroll
    for (int i = 0; i < 4; i++) {
        int n  = w * 4 + i;                // sm-local
        int gi = sc * 4096 + n * 64 + ln;  // (s,m,d) flat
        float lv = log_vars[gi];
        float mu = means[gi];
        float iv = __expf(-lv);
        float bv = -2.0f * mu * iv;
        int swz = (n & 7) << 4;
        *(ushort*)(B_l + n * 256 + ((ln * 2) ^ swz))       = f2bf(iv);
        *(ushort*)(B_l + n * 256 + ((128 + ln * 2) ^ swz)) = f2bf(bv);
        float c = fmaf(mu * mu, iv, lv);
        #pragma unroll
        for (int o = 32; o > 0; o >>= 1) c += __shfl_xor(c, o, 64);
        if (ln == 0)
            soff_l[n] = -0.5f * (c + 64.0f * LOG2PI);
    }

    // waves 8..15 of tb==0 blocks: base[sg] = 2047 * logsumexp(trans row)
    if (tb == 0 && w >= 8) {
        int sg = sc * 8 + (w - 8);
        const float* tr = trans_logits + sg * 128;
        float v0 = tr[ln], v1 = tr[ln + 64];
        float m = fmaxf(v0, v1);
        #pragma unroll
        for (int o = 32; o > 0; o >>= 1) m = fmaxf(m, __shfl_xor(m, o, 64));
        float sum = __expf(v0 - m) + __expf(v1 - m);
        #pragma unroll
        for (int o = 32; o > 0; o >>= 1) sum += __shfl_xor(sum, o, 64);
        float L = m + __logf(sum);
        float C = (m - L) + __logf(sum);
        if (ln == 0) base[sg] = 2047.0f * C;
    }
    __syncthreads();

    // wave 0: fold weight log-softmax into soff (overlaps others' MFMA)
    if (tid < 64) {
        float wl = weight_logits[sc * 64 + tid];   // [S][M] flat == sm-local
        float wm = wl;
        #pragma unroll
        for (int o = 1; o < 8; o <<= 1) wm = fmaxf(wm, __shfl_xor(wm, o, 64));
        float we = __expf(wl - wm);
        float ws = we;
        #pragma unroll
        for (int o = 1; o < 8; o <<= 1) ws += __shfl_xor(ws, o, 64);
        soff_l[tid] += wl - (wm + __logf(ws));
    }

    // ---- MFMA: C[t][n] = A @ B (k-major both sides) ------------------------
    const int lr = ln & 15;                // row (A) / col (B,C)
    const int lg = ln >> 4;                // k-group
    const int tA = wr * 16 + lr;
    const int nB = wc * 16 + lr;
    f32x4 acc = (f32x4){0.f, 0.f, 0.f, 0.f};

    #pragma unroll
    for (int kk = 0; kk < 4; kk++) {
        const int kb = kk * 64 + lg * 16;  // byte col of this lane's 8 k's
        bf16x8 af  = *(const bf16x8*)(A_l + tA * 256 + (kb ^ ((tA & 7) << 4)));
        bf16x8 bfr = *(const bf16x8*)(B_l + nB * 256 + (kb ^ ((nB & 7) << 4)));
        acc = __builtin_amdgcn_mfma_f32_16x16x32_bf16(af, bfr, acc, 0, 0, 0);
    }
    __syncthreads();   // soff_l complete (wave 0) before epilogue reads

    // ---- epilogue: em = lse over m (8 adjacent cols = 8 adjacent lanes) ----
    // C/D layout: col = ln&15, row = (ln>>4)*4 + r   [m89]
    float so = soff_l[nB];

    float psum = 0.f;
    #pragma unroll
    for (int r = 0; r < 4; r++) {
        float v = fmaf(-0.5f, acc[r], so);
        float mx = v;
        mx = fmaxf(mx, __shfl_xor(mx, 1, 64));
        mx = fmaxf(mx, __shfl_xor(mx, 2, 64));
        mx = fmaxf(mx, __shfl_xor(mx, 4, 64));
        float e = __expf(v - mx);
        e += __shfl_xor(e, 1, 64);
        e += __shfl_xor(e, 2, 64);
        e += __shfl_xor(e, 4, 64);
        psum += mx + __logf(e);
    }
    // fold the 4 row-groups (lg) -> sum over the wave's 16 t-rows
    psum += __shfl_xor(psum, 16, 64);
    psum += __shfl_xor(psum, 32, 64);
    if (ln == 0) wred[w][0] = psum;        // state wc*2
    if (ln == 8) wred[w][1] = psum;        // state wc*2+1
    __syncthreads();

    if (tid < 8) {                         // sc-local state j = tid
        int wbase = (tid >> 1) * 4;        // wc = j>>1
        int slot  = tid & 1;
        float v = wred[wbase][slot] + wred[wbase + 1][slot]
                + wred[wbase + 2][slot] + wred[wbase + 3][slot];
        part[(sc * 8 + tid) * 32 + tb] = v;
    }
}

// ---- final: out = lse_s(p + base + v) - lse_s(p), two independent lses -----
__global__ void final_kernel(const float* __restrict__ part,
                             const float* __restrict__ base,
                             const float* __restrict__ pi_logits,
                             float* __restrict__ out) {
    __shared__ float pm[2], qm[2], ps[2], qs[2];
    int tid = threadIdx.x;                // 128 threads, 2 waves
    int wv = tid >> 6, ln = tid & 63;

    float p = pi_logits[tid];
    float v = 0.f;
    const float4* p4 = (const float4*)(part + tid * 32);
    #pragma unroll
    for (int j = 0; j < 8; j++) {
        float4 a = p4[j];
        v += ((a.x + a.y) + (a.z + a.w));
    }
    float q = p + base[tid] + v;

    float mp = p, mq = q;
    #pragma unroll
    for (int o = 32; o > 0; o >>= 1) {
        mp = fmaxf(mp, __shfl_xor(mp, o, 64));
        mq = fmaxf(mq, __shfl_xor(mq, o, 64));
    }
    if (ln == 0) { pm[wv] = mp; qm[wv] = mq; }
    __syncthreads();
    float gp = fmaxf(pm[0], pm[1]);
    float gq = fmaxf(qm[0], qm[1]);
    float ep = __expf(p - gp);
    float eq = __expf(q - gq);
    #pragma unroll
    for (int o = 32; o > 0; o >>= 1) {
        ep += __shfl_xor(ep, o, 64);
        eq += __shfl_xor(eq, o, 64);
    }
    if (ln == 0) { ps[wv] = ep; qs[wv] = eq; }
    __syncthreads();
    if (tid == 0) {
        float lsep = gp + __logf(ps[0] + ps[1]);
        float lseq = gq + __logf(qs[0] + qs[1]);
        out[0] = lseq - lsep;
    }
}

extern "C" void kernel_launch(void* const* d_in, const int* in_sizes, int n_in,
                              void* d_out, int out_size, void* d_ws, size_t ws_size,
                              hipStream_t stream) {
    const float* X      = (const float*)d_in[0];
    const float* pi_l   = (const float*)d_in[1];
    const float* trans  = (const float*)d_in[2];
    const float* weight = (const float*)d_in[3];
    const float* means  = (const float*)d_in[4];
    const float* lvars  = (const float*)d_in[5];
    float* out = (float*)d_out;

    float* ws_part = (float*)d_ws;          // 128*32
    float* ws_base = ws_part + 4096;        // 128

    emis_mfma_kernel<<<512, 1024, 0, stream>>>(X, means, lvars, weight, trans,
                                               ws_part, ws_base);
    final_kernel<<<1, 128, 0, stream>>>(ws_part, ws_base, pi_l, out);
}

// Round 9
// 13.574 us; speedup vs baseline: 1.2135x; 1.2135x over previous
//
#include <hip/hip_runtime.h>
#include <hip/hip_bf16.h>
#include <math.h>

#define LOG2PI 1.8378770664093453f

typedef __attribute__((ext_vector_type(8))) short bf16x8;
typedef __attribute__((ext_vector_type(4))) float f32x4;

__device__ __forceinline__ ushort f2bf(float f) {
    __hip_bfloat16 h = __float2bfloat16(f);
    return *reinterpret_cast<ushort*>(&h);
}

// ws layout (floats): part[128*16] | base[128]

// grid = 256 blocks: tb = bid & 15 (t-chunk of 128), sc = bid >> 4 (8 states
// = 64 sm columns). 1024 threads = 16 waves (4/SIMD). wave w (wr=w&7,
// wc=w>>3) owns C rows [wr*16,+16) x cols [wc*32,+32).
// GEMM K=192: k=[x^2 | x | 1] . [iv | -2 mu iv | mu^2 iv + lv], so the
// per-(s,m) const reduction rides the matrix pipe (no shuffle chains).
__global__ __launch_bounds__(1024) void emis_mfma_kernel(
    const float* __restrict__ X,
    const float* __restrict__ means,
    const float* __restrict__ log_vars,
    const float* __restrict__ weight_logits,
    const float* __restrict__ trans_logits,
    float* __restrict__ part,              // [128*16]
    float* __restrict__ base) {            // [128]
    // A: [128 t][128 k] bf16, row stride 256B, XOR-swizzled
    // B: [64 n][128 k] bf16, row stride 256B, XOR-swizzled
    // B2: [64 n][64 k] bf16, row stride 128B, XOR-swizzled (k-seg 3)
    __shared__ __align__(16) char A_l[128 * 256];
    __shared__ __align__(16) char B_l[64 * 256];
    __shared__ __align__(16) char B2_l[64 * 128];
    __shared__ float soff_l[64];
    __shared__ float wred[16][4];

    const int tb = blockIdx.x & 15;
    const int sc = blockIdx.x >> 4;
    const int tid = threadIdx.x;
    const int w  = tid >> 6;               // 0..15
    const int ln = tid & 63;
    const int wr = w & 7;                  // row tile (16 t-rows)
    const int wc = w >> 3;                 // col half (32 cols)
    const int t0 = tb * 128;

    // ---- stage A: x^2 (k=0..63), x (k=64..127), bf16, swizzled ------------
    {
        const float4* Xv = (const float4*)(X + (size_t)t0 * 64);
        #pragma unroll
        for (int p = 0; p < 2; p++) {
            int g  = p * 1024 + tid;       // float4 index in the 128x64 tile
            int r  = g >> 4;               // t row 0..127
            int d4 = g & 15;               // float4 col -> d = d4*4
            float4 x = Xv[g];
            int swz = (r & 7) << 4;
            ushort4 sq = { f2bf(x.x * x.x), f2bf(x.y * x.y),
                           f2bf(x.z * x.z), f2bf(x.w * x.w) };
            ushort4 xl = { f2bf(x.x), f2bf(x.y), f2bf(x.z), f2bf(x.w) };
            *(ushort4*)(A_l + r * 256 + ((d4 * 8) ^ swz)) = sq;
            *(ushort4*)(A_l + r * 256 + ((128 + d4 * 8) ^ swz)) = xl;
        }
    }

    // ---- stage B: iv, -2*mu*iv, mu^2*iv+lv  (NO reductions) ---------------
    #pragma unroll
    for (int i = 0; i < 4; i++) {
        int n  = w * 4 + i;                // sm-local
        int gi = sc * 4096 + n * 64 + ln;  // (s,m,d) flat
        float lv = log_vars[gi];
        float mu = means[gi];
        float iv = __expf(-lv);
        int swz = (n & 7) << 4;
        *(ushort*)(B_l  + n * 256 + ((ln * 2) ^ swz))       = f2bf(iv);
        *(ushort*)(B_l  + n * 256 + ((128 + ln * 2) ^ swz)) = f2bf(-2.0f * mu * iv);
        *(ushort*)(B2_l + n * 128 + ((ln * 2) ^ swz))       = f2bf(fmaf(mu * mu, iv, lv));
    }

    // wave 0: soff[n] = logsoftmax(weight row) - 32*log2pi (pre-barrier)
    if (tid < 64) {
        float wl = weight_logits[sc * 64 + tid];   // [S][M] flat == sm-local
        float wm = wl;
        #pragma unroll
        for (int o = 1; o < 8; o <<= 1) wm = fmaxf(wm, __shfl_xor(wm, o, 64));
        float we = __expf(wl - wm);
        float ws = we;
        #pragma unroll
        for (int o = 1; o < 8; o <<= 1) ws += __shfl_xor(ws, o, 64);
        soff_l[tid] = (wl - (wm + __logf(ws))) - 32.0f * LOG2PI;
    }

    // waves 8..15 of tb==0 blocks: base[sg] = 2047 * logsumexp(trans row)
    if (tb == 0 && w >= 8) {
        int sg = sc * 8 + (w - 8);
        const float* tr = trans_logits + sg * 128;
        float v0 = tr[ln], v1 = tr[ln + 64];
        float m = fmaxf(v0, v1);
        #pragma unroll
        for (int o = 32; o > 0; o >>= 1) m = fmaxf(m, __shfl_xor(m, o, 64));
        float sum = __expf(v0 - m) + __expf(v1 - m);
        #pragma unroll
        for (int o = 32; o > 0; o >>= 1) sum += __shfl_xor(sum, o, 64);
        float L = m + __logf(sum);
        float C = (m - L) + __logf(sum);
        if (ln == 0) base[sg] = 2047.0f * C;
    }
    __syncthreads();

    // ---- MFMA: acc[t][n] over K=192 (seg 3 A-fragment = constant 1.0) -----
    const int lr = ln & 15;                // row (A) / col (B,C)
    const int lg = ln >> 4;                // k-group
    const int tA = wr * 16 + lr;
    const int n0 = wc * 32;
    const int aswz = (tA & 7) << 4;
    bf16x8 ones;
    #pragma unroll
    for (int j = 0; j < 8; j++) ones[j] = (short)0x3F80;  // bf16 1.0

    f32x4 acc[2];
    acc[0] = (f32x4){0.f, 0.f, 0.f, 0.f};
    acc[1] = (f32x4){0.f, 0.f, 0.f, 0.f};

    #pragma unroll
    for (int kk = 0; kk < 4; kk++) {
        const int kb = kk * 64 + lg * 16;
        bf16x8 af = *(const bf16x8*)(A_l + tA * 256 + (kb ^ aswz));
        #pragma unroll
        for (int ct = 0; ct < 2; ct++) {
            int n = n0 + ct * 16 + lr;
            bf16x8 bfr = *(const bf16x8*)(B_l + n * 256 + (kb ^ ((n & 7) << 4)));
            acc[ct] = __builtin_amdgcn_mfma_f32_16x16x32_bf16(af, bfr, acc[ct], 0, 0, 0);
        }
    }
    #pragma unroll
    for (int kk = 0; kk < 2; kk++) {       // K segment 3: A == 1
        const int kb = kk * 64 + lg * 16;
        #pragma unroll
        for (int ct = 0; ct < 2; ct++) {
            int n = n0 + ct * 16 + lr;
            bf16x8 bfr = *(const bf16x8*)(B2_l + n * 128 + (kb ^ ((n & 7) << 4)));
            acc[ct] = __builtin_amdgcn_mfma_f32_16x16x32_bf16(ones, bfr, acc[ct], 0, 0, 0);
        }
    }

    // ---- epilogue: em = lse over m (8 adjacent cols = 8 adjacent lanes) ----
    // C/D layout: col = ln&15, row = (ln>>4)*4 + r   [m89]
    float so[2];
    #pragma unroll
    for (int ct = 0; ct < 2; ct++) so[ct] = soff_l[n0 + ct * 16 + lr];

    float psum[2] = {0.f, 0.f};
    #pragma unroll
    for (int ct = 0; ct < 2; ct++) {
        #pragma unroll
        for (int r = 0; r < 4; r++) {
            float v = fmaf(-0.5f, acc[ct][r], so[ct]);
            float mx = v;
            mx = fmaxf(mx, __shfl_xor(mx, 1, 64));
            mx = fmaxf(mx, __shfl_xor(mx, 2, 64));
            mx = fmaxf(mx, __shfl_xor(mx, 4, 64));
            float e = __expf(v - mx);
            e += __shfl_xor(e, 1, 64);
            e += __shfl_xor(e, 2, 64);
            e += __shfl_xor(e, 4, 64);
            psum[ct] += mx + __logf(e);
        }
    }
    // fold the 4 row-groups (lg) -> sum over the wave's 16 t-rows
    #pragma unroll
    for (int ct = 0; ct < 2; ct++) {
        psum[ct] += __shfl_xor(psum[ct], 16, 64);
        psum[ct] += __shfl_xor(psum[ct], 32, 64);
    }
    if ((ln & 7) == 0 && ln < 16) {        // lanes 0 and 8
        #pragma unroll
        for (int ct = 0; ct < 2; ct++)
            wred[w][ct * 2 + (ln >> 3)] = psum[ct];
    }
    __syncthreads();

    if (tid < 8) {                         // sc-local state j = tid
        int wbase = (tid >> 2) * 8;        // wc = j>>2
        int slot  = tid & 3;               // ct*2 + half
        float v = 0.f;
        #pragma unroll
        for (int r = 0; r < 8; r++) v += wred[wbase + r][slot];
        part[(sc * 8 + tid) * 16 + tb] = v;
    }
}

// ---- final: out = lse_s(p + base + v) - lse_s(p), two independent lses -----
__global__ void final_kernel(const float* __restrict__ part,
                             const float* __restrict__ base,
                             const float* __restrict__ pi_logits,
                             float* __restrict__ out) {
    __shared__ float pm[2], qm[2], ps[2], qs[2];
    int tid = threadIdx.x;                // 128 threads, 2 waves
    int wv = tid >> 6, ln = tid & 63;

    float p = pi_logits[tid];
    float v = 0.f;
    const float4* p4 = (const float4*)(part + tid * 16);
    #pragma unroll
    for (int j = 0; j < 4; j++) {
        float4 a = p4[j];
        v += ((a.x + a.y) + (a.z + a.w));
    }
    float q = p + base[tid] + v;

    float mp = p, mq = q;
    #pragma unroll
    for (int o = 32; o > 0; o >>= 1) {
        mp = fmaxf(mp, __shfl_xor(mp, o, 64));
        mq = fmaxf(mq, __shfl_xor(mq, o, 64));
    }
    if (ln == 0) { pm[wv] = mp; qm[wv] = mq; }
    __syncthreads();
    float gp = fmaxf(pm[0], pm[1]);
    float gq = fmaxf(qm[0], qm[1]);
    float ep = __expf(p - gp);
    float eq = __expf(q - gq);
    #pragma unroll
    for (int o = 32; o > 0; o >>= 1) {
        ep += __shfl_xor(ep, o, 64);
        eq += __shfl_xor(eq, o, 64);
    }
    if (ln == 0) { ps[wv] = ep; qs[wv] = eq; }
    __syncthreads();
    if (tid == 0) {
        float lsep = gp + __logf(ps[0] + ps[1]);
        float lseq = gq + __logf(qs[0] + qs[1]);
        out[0] = lseq - lsep;
    }
}

extern "C" void kernel_launch(void* const* d_in, const int* in_sizes, int n_in,
                              void* d_out, int out_size, void* d_ws, size_t ws_size,
                              hipStream_t stream) {
    const float* X      = (const float*)d_in[0];
    const float* pi_l   = (const float*)d_in[1];
    const float* trans  = (const float*)d_in[2];
    const float* weight = (const float*)d_in[3];
    const float* means  = (const float*)d_in[4];
    const float* lvars  = (const float*)d_in[5];
    float* out = (float*)d_out;

    float* ws_part = (float*)d_ws;          // 128*16
    float* ws_base = ws_part + 2048;        // 128

    emis_mfma_kernel<<<256, 1024, 0, stream>>>(X, means, lvars, weight, trans,
                                               ws_part, ws_base);
    final_kernel<<<1, 128, 0, stream>>>(ws_part, ws_base, pi_l, out);
}